// Round 4
// baseline (363.201 us; speedup 1.0000x reference)
//
#include <hip/hip_runtime.h>
#include <hip/hip_cooperative_groups.h>

namespace cg = cooperative_groups;

// PPScatter: out[b, :, y, x] = x[b, :, p] for pillars with flag==1,
// last-write-wins on duplicate (y,x) per batch (NumPy semantics -> max p wins).
//
// Inputs (setup_inputs order):
//   d_in[0]: x    float32 [B=4, C=64, P=12000]
//   d_in[1]: inds int32   [B, P, 3] = (flag, xi, yi)
// Output: float32 [B, C, H=512, W=512]
//
// R4: single cooperative kernel fusing the former 3 dispatches:
//   phase A: win[] = -1 (grid-stride int2 stores, 4 MB)
//   grid.sync()
//   phase B: atomicMax(win[b,y,x], p) for flagged pillars (48k atomics)
//   grid.sync()
//   phase C: every output element written exactly once, coalesced float4
//            (REGULAR stores — NT stores regressed in R3: 59.9 -> 62.9 us)
// 2048 blocks x 256 thr = 32 waves/CU; __launch_bounds__(256,8) guarantees
// <=64 VGPR so all 8 blocks/CU are co-resident for the cooperative launch.

#define B_ 4
#define C_ 64
#define P_ 12000
#define H_ 512
#define W_ 512
#define HW_ (H_ * W_)            // 262144 = 1<<18
#define NPILLARS (B_ * P_)       // 48000
#define NTILES 2048              // 1024 cell-slabs x 2 channel-halves

typedef float f32x4 __attribute__((ext_vector_type(4)));
typedef int   i32x4 __attribute__((ext_vector_type(4)));
typedef int   i32x2 __attribute__((ext_vector_type(2)));

__global__ __launch_bounds__(256, 8) void pp_fused_kernel(
        const float* __restrict__ x,
        const int* __restrict__ inds,
        int* __restrict__ win,
        float* __restrict__ out) {
    cg::grid_group grid = cg::this_grid();
    const int nThreads = (int)(gridDim.x * 256);
    const int gid = (int)(blockIdx.x * 256 + threadIdx.x);

    // ---- Phase A: win = -1 everywhere (1M ints, int2 per thread) ----
    i32x2* win2 = reinterpret_cast<i32x2*>(win);
    for (int i = gid; i < (B_ * HW_) / 2; i += nThreads) {
        i32x2 m; m.x = -1; m.y = -1;
        win2[i] = m;
    }
    grid.sync();

    // ---- Phase B: winner atomics ----
    for (int i = gid; i < NPILLARS; i += nThreads) {
        int b = i / P_;
        int p = i - b * P_;
        int flag = inds[i * 3 + 0];
        if (flag == 1) {
            int xi = inds[i * 3 + 1];
            int yi = inds[i * 3 + 2];
            // mode='drop' semantics: out-of-range indices are dropped
            if ((unsigned)xi < (unsigned)W_ && (unsigned)yi < (unsigned)H_) {
                atomicMax(&win[(b * H_ + yi) * W_ + xi], p);
            }
        }
    }
    grid.sync();

    // ---- Phase C: full-canvas coalesced gather ----
    // tile = (cellBlk, cHalf): 1024 cells x 32 channels per tile.
    for (int tile = (int)blockIdx.x; tile < NTILES; tile += (int)gridDim.x) {
        const int cellBlk = tile >> 1;
        const int cHalf   = tile & 1;
        const long cellIdx = (long)cellBlk * 1024 + (long)threadIdx.x * 4;
        const int b    = (int)(cellIdx >> 18);        // / HW_
        const int cell = (int)(cellIdx & (HW_ - 1));  // % HW_

        const i32x4 w4 =
            *reinterpret_cast<const i32x4*>(win + ((size_t)b << 18) + cell);

        const float* xb = x + (size_t)b * (C_ * P_) + (size_t)(cHalf * 32) * P_;
        float* ob = out + (((size_t)(b * C_ + cHalf * 32)) << 18) + cell;

        #pragma unroll 8
        for (int c = 0; c < 32; ++c) {
            const float* xc = xb + (size_t)c * P_;
            f32x4 v;
            v.x = (w4.x >= 0) ? xc[w4.x] : 0.0f;   // predicated gathers: masked
            v.y = (w4.y >= 0) ? xc[w4.y] : 0.0f;   // lanes issue no transactions
            v.z = (w4.z >= 0) ? xc[w4.z] : 0.0f;
            v.w = (w4.w >= 0) ? xc[w4.w] : 0.0f;
            *reinterpret_cast<f32x4*>(ob + ((size_t)c << 18)) = v;
        }
    }
}

extern "C" void kernel_launch(void* const* d_in, const int* in_sizes, int n_in,
                              void* d_out, int out_size, void* d_ws, size_t ws_size,
                              hipStream_t stream) {
    const float* x  = (const float*)d_in[0];
    const int* inds = (const int*)d_in[1];
    float* out      = (float*)d_out;
    int* win        = (int*)d_ws;            // B*H*W ints = 4 MB

    // Cooperative co-residency: clamp grid to what the HW can hold.
    int maxBlocksPerCU = 0;
    (void)hipOccupancyMaxActiveBlocksPerMultiprocessor(
        &maxBlocksPerCU, pp_fused_kernel, 256, 0);
    if (maxBlocksPerCU < 1) maxBlocksPerCU = 1;
    int grid = maxBlocksPerCU * 256;         // 256 CUs on MI355X
    if (grid > NTILES) grid = NTILES;

    void* args[] = { (void*)&x, (void*)&inds, (void*)&win, (void*)&out };
    (void)hipLaunchCooperativeKernel(pp_fused_kernel, dim3(grid), dim3(256),
                                     args, 0, stream);
}

// Round 5
// 57.295 us; speedup vs baseline: 6.3391x; 6.3391x over previous
//
#include <hip/hip_runtime.h>

// PPScatter: out[b, :, y, x] = x[b, :, p] for pillars with flag==1,
// last-write-wins on duplicate (y,x) per batch (NumPy semantics -> max p wins).
//
// Inputs (setup_inputs order):
//   d_in[0]: x    float32 [B=4, C=64, P=12000]
//   d_in[1]: inds int32   [B, P, 3] = (flag, xi, yi)
// Output: float32 [B, C, H=512, W=512]
//
// Structure (R0, 59.9 us — R4's cooperative fusion ran 6x slower, reverted):
//   pass 0: memset winner[B*H*W] = -1 (d_ws)
//   pass 1: atomicMax(winner[b,y,x], p) for flagged pillars  (48k atomics)
//   pass 2: full-canvas coalesced gather, every output written exactly once
//
// R5 change: gather inner loop restructured for load ILP. R4's counters
// showed VGPR_Count=16 -> compiler serialized load->select->store per
// channel (latency-bound on predicated gathers). Now channels processed in
// groups of 8: 32 scalar gathers issued before the 8 float4 stores, ~8-deep
// outstanding loads per thread. CSPLIT=2 (32ch/block, grid 2048) for
// 32 waves/CU. Regular stores (NT regressed in R3).

#define B_ 4
#define C_ 64
#define P_ 12000
#define H_ 512
#define W_ 512
#define HW_ (H_ * W_)          // 262144 = 1<<18
#define CSPLIT 2               // channel halves per cell-slab

typedef float f32x4 __attribute__((ext_vector_type(4)));
typedef int   i32x4 __attribute__((ext_vector_type(4)));

__global__ void pp_winner_kernel(const int* __restrict__ inds,
                                 int* __restrict__ win) {
    int i = blockIdx.x * blockDim.x + threadIdx.x;   // i in [0, B*P)
    if (i >= B_ * P_) return;
    int b = i / P_;
    int p = i - b * P_;
    int flag = inds[i * 3 + 0];
    if (flag == 1) {
        int xi = inds[i * 3 + 1];
        int yi = inds[i * 3 + 2];
        // mode='drop' semantics: out-of-range indices are dropped
        if ((unsigned)xi < (unsigned)W_ && (unsigned)yi < (unsigned)H_) {
            atomicMax(&win[(b * H_ + yi) * W_ + xi], p);
        }
    }
}

// Block = 256 threads; each thread owns 4 consecutive cells (float4 stores,
// fully coalesced) and 32 channels, processed as 4 groups of 8 with loads
// batched ahead of stores. Grid = (B*HW/1024)*CSPLIT = 2048 blocks.
__global__ __launch_bounds__(256) void pp_gather_kernel(
        const float* __restrict__ x,
        const int* __restrict__ win,
        float* __restrict__ out) {
    const int t = threadIdx.x;
    const int cellBlk = blockIdx.x >> 1;          // which 1024-cell slab
    const int cHalf   = blockIdx.x & 1;           // which 32-channel half
    const long cellIdx = (long)cellBlk * 1024 + (long)t * 4;
    const int b    = (int)(cellIdx >> 18);        // / HW_
    const int cell = (int)(cellIdx & (HW_ - 1));  // % HW_

    const i32x4 w4 =
        *reinterpret_cast<const i32x4*>(win + ((size_t)b << 18) + cell);

    const float* xb = x + (size_t)b * (C_ * P_) + (size_t)(cHalf * 32) * P_;
    float* ob = out + (((size_t)(b * C_ + cHalf * 32)) << 18) + cell;

    #pragma unroll
    for (int g = 0; g < 4; ++g) {
        f32x4 v[8];
        // phase 1: issue all 32 gather loads for this 8-channel group
        #pragma unroll
        for (int c = 0; c < 8; ++c) {
            const float* xc = xb + (size_t)(g * 8 + c) * P_;
            v[c].x = (w4.x >= 0) ? xc[w4.x] : 0.0f;  // predicated: masked
            v[c].y = (w4.y >= 0) ? xc[w4.y] : 0.0f;  // lanes issue no
            v[c].z = (w4.z >= 0) ? xc[w4.z] : 0.0f;  // transactions
            v[c].w = (w4.w >= 0) ? xc[w4.w] : 0.0f;
        }
        // phase 2: 8 coalesced float4 stores
        #pragma unroll
        for (int c = 0; c < 8; ++c) {
            *reinterpret_cast<f32x4*>(ob + ((size_t)(g * 8 + c) << 18)) = v[c];
        }
    }
}

extern "C" void kernel_launch(void* const* d_in, const int* in_sizes, int n_in,
                              void* d_out, int out_size, void* d_ws, size_t ws_size,
                              hipStream_t stream) {
    const float* x  = (const float*)d_in[0];
    const int* inds = (const int*)d_in[1];
    float* out      = (float*)d_out;
    int* win        = (int*)d_ws;            // B*H*W ints = 4 MB

    // winner = -1 everywhere (0xFF bytes == -1 as int32)
    (void)hipMemsetAsync(win, 0xFF, (size_t)B_ * HW_ * sizeof(int), stream);

    const int nPillars = B_ * P_;
    pp_winner_kernel<<<(nPillars + 255) / 256, 256, 0, stream>>>(inds, win);

    const int nBlocks = (B_ * HW_ / 1024) * CSPLIT;   // 2048 blocks
    pp_gather_kernel<<<nBlocks, 256, 0, stream>>>(x, win, out);
}